// Round 1
// baseline (184.533 us; speedup 1.0000x reference)
//
#include <hip/hip_runtime.h>

// Fused morphological opening (22x22 flat SE), 8x3x1024x1024 f32, one kernel.
// opening = dilate(erode(x)); separable. Per 64x64 output tile:
//   P0 : colmin streamed global->regs->LDS   (B: 86 rows x stride 116)
//   P12: rowmin -> eroded (+ -inf border override) -> rowmax, ALL IN REGS,
//        single LDS read pass + single LDS write pass (f4 I/O)
//   P3 : colmax -> coalesced global store
// v2: P1/P2 fused. Old structure did eroded -> LDS -> reload for rowmax
// (26 f4 reads + 14 f4 writes + 2 extra barriers per row-chunk); fused does
// 17 f4 reads + 6 f4 writes, 3 barriers/tile total instead of 5. Chunk
// overlaps recompute identical eroded values -> benign duplicate f4 writes.
// EVERY phase is balanced per WAVE INDEX (waves map one-per-SIMD;
// thread-range gating starves whole SIMDs across all resident blocks):
//   P0 : 54 lanes active in each of the 4 waves (consecutive cols -> coalesced)
//   P12: 255 thr = 85 rows x 3 uniform overlapping chunks (COUT=24, c0=20ch);
//        reads B cols [c0, c0+68), erodes 45, dilates 24, writes [c0, c0+24)
//   P3 : 256 thr = 64 cols x 4 chunks of 16 rows
// Read-phase | barrier | write-phase ordering handles the in-place hazard.
// B stride 116: f4 row ops start-phase 29*o mod 8 (odd) -> uniform across
// banks; scalar col ops (lanes=cols) 2-way aliased (free on CDNA4).
// Window for index i: [i-11, i+10]. Erosion pads +inf; eroded values outside
// the image are -inf for dilation (border override before rowmax).

#define HH 1024
#define WW 1024
#define KW 22
#define SB 116
#define PINF __builtin_inff()

template<bool IS_MIN>
__device__ __forceinline__ float vop(float a, float b) {
    return IS_MIN ? fminf(a, b) : fmaxf(a, b);
}

// van Herk / Gil-Werman, compile-time output count COUT (window KW=22).
// get(p): input at window-space p (output k's window = get(k..k+21)).
template<bool IS_MIN, int COUT, class Get, class Put>
__device__ __forceinline__ void vanherk(Get get, Put put) {
    constexpr int NIN = COUT + KW - 1;
    constexpr int NB = (NIN + KW - 1) / KW;
    const float ID = IS_MIN ? PINF : -PINF;
    float Sprev[KW];
    #pragma unroll
    for (int j = 0; j < NB; ++j) {
        const int base = KW * j;
        const int needed = (NIN - base) < KW ? (NIN - base) : KW;
        float v[KW];
        #pragma unroll
        for (int m = 0; m < KW; ++m)
            if (m < needed) v[m] = get(base + m);
        float p = ID;
        #pragma unroll
        for (int m = 0; m < KW; ++m) {
            if (m < needed) {
                p = vop<IS_MIN>(p, v[m]);
                const int k = base - (KW - 1) + m;
                if (k >= 0 && k < COUT) {
                    if (m == KW - 1) put(k, p);
                    else             put(k, vop<IS_MIN>(Sprev[m + 1], p));
                }
            }
        }
        if (j < NB - 1) {
            float s = ID;
            #pragma unroll
            for (int m = KW - 1; m >= 0; --m) {
                s = vop<IS_MIN>(s, v[m]);
                Sprev[m] = s;
            }
        }
    }
}

template<bool INTERIOR>
__device__ __forceinline__ void tile_body(const float* __restrict__ src,
                                          float* __restrict__ dst,
                                          int R, int C, float* B, int t) {
    const int w = t >> 6, slot = t & 63;

    // ---- P0: colmin, global -> B rows [0,86) x cols j in [0,108). ----
    // B row o = img row R-11+o; window = img rows [R-22+o, R-1+o].
    // wave = 2*rowchunk + colhalf; lanes 0..53 = consecutive cols.
    if (slot < 54) {
        const int ch = w >> 1;
        const int j = (w & 1) * 54 + slot;
        const int base_o = ch * 43;
        int cj = C - 22 + j;
        bool colOK = true;
        if (!INTERIOR) {
            colOK = (unsigned)cj < WW;
            cj = cj < 0 ? 0 : (cj > WW - 1 ? WW - 1 : cj);
        }
        const float* col = src + cj;
        const int rbase = R - 22 + base_o;
        vanherk<true, 43>(
            [&](int p) {
                int r = rbase + p;
                if (INTERIOR) return col[r * WW];
                int rc = r < 0 ? 0 : (r > HH - 1 ? HH - 1 : r);
                float vv = col[rc * WW];
                return (colOK && (unsigned)r < HH) ? vv : PINF;
            },
            [&](int k, float vv) { B[(base_o + k) * SB + j] = vv; });
    }
    __syncthreads();

    // ---- P12: fused rowmin -> border override -> rowmax, in regs. ----
    // 85 rows (o = B row = img row R-11+o) x 3 chunks, COUT=24, c0=20ch.
    // rowmax[c] (c = out col local) = max over eroded e in [c, c+21];
    // eroded[e] = min over B cols [e, e+21]. Chunk needs eroded [c0,c0+45)
    // hence B cols [c0, c0+66) -> read 17 f4 = [c0, c0+68) (<=108 at c0=40).
    // Reads all to regs, compute, barrier, then write: in-place safe.
    {
        const bool act = t < 255;
        const int ch = (3 * t + 2) >> 8;          // t/85 for t<255
        const int o = t - 85 * ch;
        const int g0 = 5 * ch;                    // c0 = 20ch = 4*g0
        const int c0 = 20 * ch;
        float* Brow = B + o * SB;
        float in12[68];
        if (act) {
            #pragma unroll
            for (int i = 0; i < 17; ++i) {        // B cols [20ch, 20ch+68)
                float4 x = ((const float4*)Brow)[g0 + i];
                in12[4 * i] = x.x; in12[4 * i + 1] = x.y;
                in12[4 * i + 2] = x.z; in12[4 * i + 3] = x.w;
            }
        }
        float rx[24];
        if (act) {
            float er[45];
            vanherk<true, 45>(
                [&](int p) { return in12[p]; },
                [&](int k, float vv) { er[k] = vv; });
            if (!INTERIOR) {
                // eroded positions outside the image are -inf for dilation
                const bool rOK = (unsigned)(R - 11 + o) < HH;
                #pragma unroll
                for (int k = 0; k < 45; ++k) {
                    const int cimg = C - 11 + c0 + k;
                    if (!rOK || (unsigned)cimg >= WW) er[k] = -PINF;
                }
            }
            vanherk<false, 24>(
                [&](int p) { return er[p]; },
                [&](int k, float vv) { rx[k] = vv; });
        }
        __syncthreads();                          // all reads before any write
        if (act) {
            #pragma unroll
            for (int i = 0; i < 6; ++i)           // rowmax cols [20ch, 20ch+24)
                ((float4*)Brow)[g0 + i] =
                    make_float4(rx[4 * i], rx[4 * i + 1],
                                rx[4 * i + 2], rx[4 * i + 3]);
        }
        __syncthreads();
    }

    // ---- P3: colmax -> out. 64 cols x 4 chunks of 16 rows (all waves). ----
    // out row R+y: window = B rows [y, y+21] (rows 0..84 hold rowmax).
    {
        const int c = t & 63;
        const int y0 = (t >> 6) << 4;             // {0,16,32,48}
        float o16[16];
        vanherk<false, 16>(
            [&](int p) { return B[(y0 + p) * SB + c]; },
            [&](int k, float vv) { o16[k] = vv; });
        #pragma unroll
        for (int k = 0; k < 16; ++k)
            dst[(R + y0 + k) * WW + C + c] = o16[k];
    }
}

__global__ __launch_bounds__(256, 4) void fused_open(const float* __restrict__ in,
                                                     float* __restrict__ out) {
    __shared__ float B[86 * SB];                  // 39,904 B -> 4 blk/CU
    const int t = threadIdx.x;
    const int b = blockIdx.x;
    const int plane = b >> 8;
    const int by = (b >> 4) & 15;
    const int bx = b & 15;
    const int R = by * 64, C = bx * 64;
    const float* src = in + (size_t)plane * (HH * WW);
    float* dst = out + (size_t)plane * (HH * WW);

    if (by >= 1 && by <= 14 && bx >= 1 && bx <= 14)
        tile_body<true>(src, dst, R, C, B, t);
    else
        tile_body<false>(src, dst, R, C, B, t);
}

extern "C" void kernel_launch(void* const* d_in, const int* in_sizes, int n_in,
                              void* d_out, int out_size, void* d_ws, size_t ws_size,
                              hipStream_t stream) {
    const float* in = (const float*)d_in[0];
    float* out = (float*)d_out;
    (void)d_ws; (void)ws_size;
    fused_open<<<24 * 16 * 16, 256, 0, stream>>>(in, out);
}